// Round 13
// baseline (1785.770 us; speedup 1.0000x reference)
//
#include <hip/hip_runtime.h>
#include <hip/hip_bf16.h>
#include <cstddef>

// Problem constants
#define NBLK 8
#define DD   128
#define DI   256
#define NH   4
#define PP   64
#define NNs  32
#define EE   580      // D_IN_PROJ
#define BB   2
#define LLEN 4096
#define ML   (BB*LLEN)   // 8192 rows
#define SEGS 256
#define TT   16          // SEGS*TT == LLEN
#define GPAD 264         // padded bf16 row stride

typedef unsigned short u16;
typedef short bf16x8 __attribute__((ext_vector_type(8)));
typedef float f32x4 __attribute__((ext_vector_type(4)));

__device__ __forceinline__ float siluf(float x){ return x / (1.f + expf(-x)); }
__device__ __forceinline__ float b2f(u16 u){ return __uint_as_float((unsigned)u << 16); }
__device__ __forceinline__ u16 f2b(float f){
    __hip_bfloat16 h = __float2bfloat16(f);   // RNE
    return *reinterpret_cast<u16*>(&h);
}
__device__ __forceinline__ void ld8f(const u16* p, float* f){
    ushort4 a = *(const ushort4*)p;
    ushort4 b = *(const ushort4*)(p + 4);
    f[0]=b2f(a.x); f[1]=b2f(a.y); f[2]=b2f(a.z); f[3]=b2f(a.w);
    f[4]=b2f(b.x); f[5]=b2f(b.y); f[6]=b2f(b.z); f[7]=b2f(b.w);
}
__device__ __forceinline__ float waveReduceSum(float v){
#pragma unroll
    for (int off = 32; off > 0; off >>= 1) v += __shfl_xor(v, off, 64);
    return v;
}

// ---------------- weights f32 -> bf16 + x copy (once per launch) ----------------
#define IPW_N (NBLK*EE*DD)
#define OPW_N (NBLK*DD*DI)
#define F1W_N (NBLK*512*DD)
#define F2W_N (NBLK*DD*DI)
#define CVT_TOT (IPW_N+OPW_N+F1W_N+F2W_N)   // 1642496 = 256*6416

__global__ __launch_bounds__(256) void cvt_weights(const float* __restrict__ ip,
                                                   const float* __restrict__ op,
                                                   const float* __restrict__ f1,
                                                   const float* __restrict__ f2,
                                                   const float* __restrict__ xin,
                                                   u16* __restrict__ dip,
                                                   u16* __restrict__ dop,
                                                   u16* __restrict__ df1,
                                                   u16* __restrict__ df2,
                                                   float* __restrict__ xout)
{
    int i = blockIdx.x * 256 + threadIdx.x;
    if (i < IPW_N)                          dip[i] = f2b(ip[i]);
    else if (i < IPW_N + OPW_N)             dop[i - IPW_N] = f2b(op[i - IPW_N]);
    else if (i < IPW_N + OPW_N + F1W_N)     df1[i - IPW_N - OPW_N] = f2b(f1[i - IPW_N - OPW_N]);
    else                                    df2[i - IPW_N - OPW_N - F1W_N] = f2b(f2[i - IPW_N - OPW_N - F1W_N]);
    if (i < ML * DD) xout[i] = xin[i];
}

// ================= Fused LN1 + in_proj GEMM (bf16 out), 2 n-tiles per block =================
// grid (5, ML/64); C[ML][EE] bf16 = LN(X) @ W^T ; K=DD=128
__global__ __launch_bounds__(256) void inproj_ln_gemm(const float* __restrict__ X,
                                                      const float* __restrict__ lnw,
                                                      const float* __restrict__ lnb,
                                                      const u16* __restrict__ W,
                                                      u16* __restrict__ C)
{
    __shared__ __align__(16) u16 Ash[64*128];
    __shared__ __align__(16) u16 Wsh[64*128];
    __shared__ float red[64][8];
    const int tid = threadIdx.x;
    const int wave = tid >> 6, lane = tid & 63;
    const int l15 = lane & 15, quad = lane >> 4;
    const int bm = blockIdx.y * 64;
    const int lrow = tid >> 2, sub = tid & 3;

    // LN prologue (once per block)
    const float* xr = X + (size_t)(bm + lrow) * DD + sub*32;
    float4 xv[8];
    float ps = 0.f, pq = 0.f;
#pragma unroll
    for (int i = 0; i < 8; i++) {
        xv[i] = *(const float4*)(xr + i*4);
        ps += xv[i].x + xv[i].y + xv[i].z + xv[i].w;
        pq += xv[i].x*xv[i].x + xv[i].y*xv[i].y + xv[i].z*xv[i].z + xv[i].w*xv[i].w;
    }
    red[lrow][sub] = ps; red[lrow][4+sub] = pq;
    __syncthreads();
    float s = red[lrow][0]+red[lrow][1]+red[lrow][2]+red[lrow][3];
    float q = red[lrow][4]+red[lrow][5]+red[lrow][6]+red[lrow][7];
    float mu = s * (1.f/DD);
    float rstd = rsqrtf(q*(1.f/DD) - mu*mu + 1e-5f);
#pragma unroll
    for (int i = 0; i < 4; i++) {
        float4 a0 = xv[2*i], a1 = xv[2*i+1];
        int c0 = sub*32 + i*8;
        u16 o[8];
        o[0] = f2b((a0.x-mu)*rstd*lnw[c0+0] + lnb[c0+0]);
        o[1] = f2b((a0.y-mu)*rstd*lnw[c0+1] + lnb[c0+1]);
        o[2] = f2b((a0.z-mu)*rstd*lnw[c0+2] + lnb[c0+2]);
        o[3] = f2b((a0.w-mu)*rstd*lnw[c0+3] + lnb[c0+3]);
        o[4] = f2b((a1.x-mu)*rstd*lnw[c0+4] + lnb[c0+4]);
        o[5] = f2b((a1.y-mu)*rstd*lnw[c0+5] + lnb[c0+5]);
        o[6] = f2b((a1.z-mu)*rstd*lnw[c0+6] + lnb[c0+6]);
        o[7] = f2b((a1.w-mu)*rstd*lnw[c0+7] + lnb[c0+7]);
        *(uint4*)&Ash[((size_t)(sub*4+i)*64 + lrow) * 8] = *(uint4*)o;
    }

    // two n-tiles sharing the LN'd A tile
#pragma unroll 1
    for (int t2 = 0; t2 < 2; t2++) {
        int bn = (blockIdx.x * 2 + t2) * 64;
        __syncthreads();   // Ash ready / prior readers of Wsh done
#pragma unroll
        for (int i = 0; i < 4; i++) {
            int k8 = sub + 4*i;
            uint4 wv = make_uint4(0u,0u,0u,0u);
            if (bn + lrow < EE)
                wv = *(const uint4*)(W + (size_t)(bn + lrow) * DD + k8*8);
            *(uint4*)&Wsh[((size_t)k8*64 + lrow) * 8] = wv;
        }
        __syncthreads();

        f32x4 acc[4];
#pragma unroll
        for (int nt = 0; nt < 4; nt++) acc[nt] = (f32x4){0.f,0.f,0.f,0.f};
#pragma unroll
        for (int kk = 0; kk < 4; kk++) {
            bf16x8 af = *(const bf16x8*)&Ash[(((kk*4 + quad)*64) + wave*16 + l15) * 8];
#pragma unroll
            for (int nt = 0; nt < 4; nt++) {
                bf16x8 bfv = *(const bf16x8*)&Wsh[(((kk*4 + quad)*64) + nt*16 + l15) * 8];
                acc[nt] = __builtin_amdgcn_mfma_f32_16x16x32_bf16(af, bfv, acc[nt], 0, 0, 0);
            }
        }
#pragma unroll
        for (int nt = 0; nt < 4; nt++) {
            int n = bn + nt*16 + l15;
            if (n < EE) {
#pragma unroll
                for (int r = 0; r < 4; r++) {
                    int m = bm + wave*16 + quad*4 + r;
                    C[(size_t)m * EE + n] = f2b(acc[nt][r]);
                }
            }
        }
    }
}

// ================= Scan pass 1: inline conv + local scan, 4 segs/block (bf16 state) =================
__global__ __launch_bounds__(256) void scan1(const u16* __restrict__ zx,
                                             const float* __restrict__ cw,
                                             const float* __restrict__ cb,
                                             const float* __restrict__ dt_bias,
                                             const float* __restrict__ A_log,
                                             u16* __restrict__ seg,
                                             float* __restrict__ segsum)
{
    __shared__ float Bsh[4][TT*NNs];
    __shared__ float dts[4][TT], das[4][TT];
    int wv = threadIdx.x >> 6;
    int p = threadIdx.x & 63;
    int sg = blockIdx.x % (SEGS/4);
    int bh = blockIdx.x / (SEGS/4);
    int h = bh % NH;
    int b = bh / NH;
    int s = sg*4 + wv;
    int l0 = s * TT;
    int row0 = b * LLEN + l0;

    float xr[TT+3];
    const u16* xcol = zx + (size_t)row0 * EE + 256 + h*64 + p;
#pragma unroll
    for (int r = 0; r < TT+3; r++) {
        int l = l0 - 3 + r;
        xr[r] = (l >= 0) ? b2f(xcol[(ptrdiff_t)(r-3) * EE]) : 0.f;
    }
    float4 wx = *(const float4*)(cw + (size_t)(h*64+p) * 4);
    float cbx = cb[h*64+p];

    if (p < NNs) {   // B conv, column p
        float br[TT+3];
        const u16* bcol = zx + (size_t)row0 * EE + 512 + p;
#pragma unroll
        for (int r = 0; r < TT+3; r++) {
            int l = l0 - 3 + r;
            br[r] = (l >= 0) ? b2f(bcol[(ptrdiff_t)(r-3) * EE]) : 0.f;
        }
        float4 wb = *(const float4*)(cw + (size_t)(256+p) * 4);
        float cbb = cb[256+p];
#pragma unroll
        for (int t = 0; t < TT; t++)
            Bsh[wv][t*NNs + p] = siluf(cbb + wb.x*br[t] + wb.y*br[t+1] + wb.z*br[t+2] + wb.w*br[t+3]);
    }
    if (p < TT) {
        float v = b2f(zx[(size_t)(row0+p)*EE + (EE-NH) + h]) + dt_bias[h];
        float dt = (v > 20.f) ? v : log1pf(expf(v));
        dts[wv][p] = dt;
        das[wv][p] = expf(-expf(A_log[h]) * dt);
    }
    __syncthreads();

    float hreg[NNs];
#pragma unroll
    for (int n = 0; n < NNs; n++) hreg[n] = 0.f;
    float sdt = 0.f;
#pragma unroll
    for (int t = 0; t < TT; t++) {
        float dA = das[wv][t];
        float dt = dts[wv][t];
        float xv = siluf(cbx + wx.x*xr[t] + wx.y*xr[t+1] + wx.z*xr[t+2] + wx.w*xr[t+3]);
        float dtx = dt * xv;
#pragma unroll
        for (int n4 = 0; n4 < 8; n4++) {
            float4 Bv = *(const float4*)&Bsh[wv][t*NNs + n4*4];
            hreg[n4*4+0] = fmaf(hreg[n4*4+0], dA, dtx * Bv.x);
            hreg[n4*4+1] = fmaf(hreg[n4*4+1], dA, dtx * Bv.y);
            hreg[n4*4+2] = fmaf(hreg[n4*4+2], dA, dtx * Bv.z);
            hreg[n4*4+3] = fmaf(hreg[n4*4+3], dA, dtx * Bv.w);
        }
        sdt += dt;
    }
    int bidg = bh * SEGS + s;
    u16* dst = seg + ((size_t)bidg * PP + p) * NNs;
#pragma unroll
    for (int n8 = 0; n8 < 4; n8++) {
        u16 ob[8];
#pragma unroll
        for (int j = 0; j < 8; j++) ob[j] = f2b(hreg[n8*8 + j]);
        *(uint4*)(dst + n8*8) = *(uint4*)ob;
    }
    if (p == 0) segsum[bidg] = sdt;
}

// ================= Scan pass 2: cross-segment combine (bf16 state, f32 chain) =================
__global__ __launch_bounds__(256) void scan2(u16* __restrict__ seg,
                                             const float* __restrict__ segsum,
                                             const float* __restrict__ A_log)
{
    int bh = blockIdx.x >> 3;
    int chunk = blockIdx.x & 7;
    int h = bh % NH;
    int entry = chunk * 256 + threadIdx.x;   // 0..2047
    float negA = -expf(A_log[h]);
    float hs = 0.f;
    const float* ss = segsum + bh * SEGS;
    u16* base = seg + (size_t)bh * SEGS * (PP * NNs) + entry;
    for (int j0 = 0; j0 < SEGS; j0 += 16) {
        float e[16], a[16];
#pragma unroll
        for (int k = 0; k < 16; k++) {
            a[k] = ss[j0 + k];
            e[k] = b2f(base[(size_t)(j0 + k) * (PP * NNs)]);
        }
#pragma unroll
        for (int k = 0; k < 16; k++) {
            float Aj = expf(negA * a[k]);
            base[(size_t)(j0 + k) * (PP * NNs)] = f2b(hs);
            hs = fmaf(Aj, hs, e[k]);
        }
    }
}

// ================= scan3_g: re-scan + gate(silu z) + rms_w scale, emit G bf16 + rl =================
// grid BB*SEGS = 512 blocks x 256 threads; block = (b, seg) = 16 rows, wave = head.
__global__ __launch_bounds__(256) void scan3_g(const u16* __restrict__ zx,
                                               const float* __restrict__ cw,
                                               const float* __restrict__ cb,
                                               const float* __restrict__ dt_bias,
                                               const float* __restrict__ A_log,
                                               const u16* __restrict__ seg,
                                               const float* __restrict__ Dp,
                                               const float* __restrict__ rmsw,
                                               u16* __restrict__ G,
                                               float* __restrict__ rlg)
{
    __shared__ float BCsh[4*1024];
    __shared__ float dts[4*16], das[4*16];
    __shared__ float part[16*4];
    const int tid = threadIdx.x;
    const int wv = tid >> 6, p = tid & 63;
    const int s = blockIdx.x % SEGS;
    const int b = blockIdx.x / SEGS;
    const int h = wv;
    const int l0 = s * TT;
    const int row0 = b * LLEN + l0;

    float xr[TT+3];
    const u16* xcol = zx + (size_t)row0*EE + 256 + h*64 + p;
#pragma unroll
    for (int r = 0; r < TT+3; r++) {
        int l = l0 - 3 + r;
        xr[r] = (l >= 0) ? b2f(xcol[(ptrdiff_t)(r-3)*EE]) : 0.f;
    }
    float4 wx = *(const float4*)(cw + (size_t)(h*64+p)*4);
    float cbx = cb[h*64+p];
    {   // B/C conv, channel 256+p (redundant across waves; verified pattern)
        float br[TT+3];
        const u16* bcol = zx + (size_t)row0*EE + 512 + p;
#pragma unroll
        for (int r = 0; r < TT+3; r++) {
            int l = l0 - 3 + r;
            br[r] = (l >= 0) ? b2f(bcol[(ptrdiff_t)(r-3)*EE]) : 0.f;
        }
        float4 wb = *(const float4*)(cw + (size_t)(256+p)*4);
        float cbb = cb[256+p];
#pragma unroll
        for (int t = 0; t < TT; t++)
            BCsh[wv*1024 + t*64 + p] = siluf(cbb + wb.x*br[t] + wb.y*br[t+1] + wb.z*br[t+2] + wb.w*br[t+3]);
    }
    if (p < TT) {
        float v = b2f(zx[(size_t)(row0+p)*EE + (EE-NH) + h]) + dt_bias[h];
        float dt = (v > 20.f) ? v : log1pf(expf(v));
        dts[wv*16 + p] = dt;
        das[wv*16 + p] = expf(-expf(A_log[h]) * dt);
    }
    float hreg[NNs];
    {
        int bidg = (b*NH + h)*SEGS + s;
        const u16* src = seg + ((size_t)bidg*PP + p)*NNs;
#pragma unroll
        for (int n8 = 0; n8 < 4; n8++) {
            float f[8];
            ld8f(src + n8*8, f);
#pragma unroll
            for (int j = 0; j < 8; j++) hreg[n8*8 + j] = f[j];
        }
    }
    float dpv = Dp[h];
    const u16* zcol = zx + (size_t)row0*EE + h*64 + p;    // z section cols 0..255
    __syncthreads();

    float gs[TT];
#pragma unroll
    for (int t = 0; t < TT; t++) {
        float dA = das[wv*16 + t];
        float dt = dts[wv*16 + t];
        float xv = siluf(cbx + wx.x*xr[t] + wx.y*xr[t+1] + wx.z*xr[t+2] + wx.w*xr[t+3]);
        float dtx = dt * xv;
        float acc = 0.f;
#pragma unroll
        for (int n4 = 0; n4 < 8; n4++) {
            float4 Bv = *(const float4*)&BCsh[wv*1024 + t*64 + n4*4];
            float4 Cv = *(const float4*)&BCsh[wv*1024 + t*64 + 32 + n4*4];
            hreg[n4*4+0] = fmaf(hreg[n4*4+0], dA, dtx * Bv.x);
            hreg[n4*4+1] = fmaf(hreg[n4*4+1], dA, dtx * Bv.y);
            hreg[n4*4+2] = fmaf(hreg[n4*4+2], dA, dtx * Bv.z);
            hreg[n4*4+3] = fmaf(hreg[n4*4+3], dA, dtx * Bv.w);
            acc = fmaf(hreg[n4*4+0], Cv.x, acc);
            acc = fmaf(hreg[n4*4+1], Cv.y, acc);
            acc = fmaf(hreg[n4*4+2], Cv.z, acc);
            acc = fmaf(hreg[n4*4+3], Cv.w, acc);
        }
        float y = acc + dpv * xv;
        gs[t] = y * siluf(b2f(zcol[(ptrdiff_t)t * EE]));
    }
    {
        int c = h*64 + p;
        float rw = rmsw[c];
#pragma unroll
        for (int t = 0; t < TT; t++) {
            float w = waveReduceSum(gs[t]*gs[t]);
            if (p == 0) part[t*4 + wv] = w;
            G[(size_t)(row0 + t)*DI + c] = f2b(gs[t] * rw);
        }
    }
    __syncthreads();
    if (tid < TT) {
        float qq = part[tid*4+0] + part[tid*4+1] + part[tid*4+2] + part[tid*4+3];
        rlg[row0 + tid] = rsqrtf(qq * (1.f/DI) + 1e-5f);
    }
}

// ================= out_proj GEMM with row scale: Xm = rl * (G @ W^T) + resid (BM=32) =================
// grid (2, ML/32)
__global__ __launch_bounds__(256) void grms_outproj_gemm(const u16* __restrict__ G,
                                                         const float* __restrict__ rlg,
                                                         const u16* __restrict__ W,
                                                         const float* __restrict__ resid,
                                                         float* __restrict__ C)
{
    __shared__ __align__(16) u16 Ash[32*256];
    __shared__ __align__(16) u16 Wsh[64*256];
    __shared__ float rl[32];
    const int tid = threadIdx.x;
    const int wave = tid >> 6, lane = tid & 63;
    const int l15 = lane & 15, quad = lane >> 4;
    const int rt = wave & 1, nq = wave >> 1;
    const int bm = blockIdx.y * 32;
    const int bn = blockIdx.x * 64;

    {
        int wrow = tid >> 2, ksub = tid & 3;
#pragma unroll
        for (int i = 0; i < 8; i++) {
            int k8 = ksub + 4*i;
            uint4 wv = *(const uint4*)(W + (size_t)(bn + wrow) * DI + k8*8);
            *(uint4*)&Wsh[((size_t)k8*64 + wrow) * 8] = wv;
        }
    }
    int lrow = tid >> 3, sub = tid & 7;
    const u16* gr = G + (size_t)(bm + lrow) * DI + sub*32;
#pragma unroll
    for (int i = 0; i < 4; i++)
        *(uint4*)&Ash[((size_t)(sub*4 + i)*32 + lrow) * 8] = *(const uint4*)(gr + i*8);
    if (sub == 0) rl[lrow] = rlg[bm + lrow];
    __syncthreads();

    f32x4 acc[2];
    acc[0] = (f32x4){0.f,0.f,0.f,0.f};
    acc[1] = (f32x4){0.f,0.f,0.f,0.f};
#pragma unroll
    for (int kk = 0; kk < 8; kk++) {
        bf16x8 af = *(const bf16x8*)&Ash[(((kk*4 + quad)*32) + rt*16 + l15) * 8];
#pragma unroll
        for (int nt = 0; nt < 2; nt++) {
            bf16x8 bfv = *(const bf16x8*)&Wsh[(((kk*4 + quad)*64) + nq*32 + nt*16 + l15) * 8];
            acc[nt] = __builtin_amdgcn_mfma_f32_16x16x32_bf16(af, bfv, acc[nt], 0, 0, 0);
        }
    }
#pragma unroll
    for (int nt = 0; nt < 2; nt++) {
        int n = bn + nq*32 + nt*16 + l15;
#pragma unroll
        for (int r = 0; r < 4; r++) {
            int lm = rt*16 + quad*4 + r;
            int m = bm + lm;
            C[(size_t)m * DD + n] = acc[nt][r] * rl[lm] + resid[(size_t)m * DD + n];
        }
    }
}

// ================= Fused MLP (BM=32, 512 threads / 8 waves), Xm cached in LDS =================
// grid ML/32; wave w: mt = w&1 (m-tile), ng = w>>1 (n-group)
__global__ __launch_bounds__(512) void mlp_fused(const float* __restrict__ Xm,
                                                 const float* __restrict__ lnw,
                                                 const float* __restrict__ lnb,
                                                 const u16* __restrict__ W1,   // 512 x 128
                                                 const float* __restrict__ b1, // 512
                                                 const u16* __restrict__ W2,   // 128 x 256
                                                 const float* __restrict__ b2, // 128
                                                 float* __restrict__ Out,
                                                 float* __restrict__ out2)     // null except last layer
{
    __shared__ __align__(16) u16 Ash[32*128];    // 8 KB
    __shared__ __align__(16) u16 Wsh[128*128];   // 32 KB
    __shared__ __align__(16) u16 Gsh[32*GPAD];   // 16.5 KB
    __shared__ float Xsh[32*132];                // 16.9 KB (Xm cache)
    __shared__ float red[32][32];
    const int tid = threadIdx.x;
    const int wv = tid >> 6, lane = tid & 63;
    const int l15 = lane & 15, quad = lane >> 4;
    const int mt = wv & 1, ng = wv >> 1;
    const int bm = blockIdx.x * 32;

    {
        int lrow = tid >> 4, sub = tid & 15;
        const float* xr = Xm + (size_t)(bm + lrow) * DD + sub*8;
        float4 x0 = *(const float4*)xr;
        float4 x1 = *(const float4*)(xr + 4);
        *(float4*)&Xsh[lrow*132 + sub*8]     = x0;
        *(float4*)&Xsh[lrow*132 + sub*8 + 4] = x1;
        float ps = x0.x+x0.y+x0.z+x0.w + x1.x+x1.y+x1.z+x1.w;
        float pq = x0.x*x0.x+x0.y*x0.y+x0.z*x0.z+x0.w*x0.w
                 + x1.x*x1.x+x1.y*x1.y+x1.z*x1.z+x1.w*x1.w;
        red[lrow][sub] = ps; red[lrow][16+sub] = pq;
        __syncthreads();
        float s = 0.f, q = 0.f;
#pragma unroll
        for (int j = 0; j < 16; j++) { s += red[lrow][j]; q += red[lrow][16+j]; }
        float mu = s * (1.f/DD);
        float rstd = rsqrtf(q*(1.f/DD) - mu*mu + 1e-5f);
        int c0 = sub*8;
        float xa[8] = {x0.x,x0.y,x0.z,x0.w,x1.x,x1.y,x1.z,x1.w};
        u16 o[8];
#pragma unroll
        for (int j = 0; j < 8; j++)
            o[j] = f2b((xa[j]-mu)*rstd*lnw[c0+j] + lnb[c0+j]);
        *(uint4*)&Ash[((size_t)sub*32 + lrow) * 8] = *(uint4*)o;
    }
    __syncthreads();

    bf16x8 afr[4];
#pragma unroll
    for (int kk = 0; kk < 4; kk++)
        afr[kk] = *(const bf16x8*)&Ash[(((kk*4 + quad)*32) + mt*16 + l15) * 8];

    for (int p = 0; p < 4; p++) {
        __syncthreads();
        {
            int wrow = tid >> 2, ksub = tid & 3;   // 128 rows
            int r1 = (wrow < 64) ? (p*64 + wrow) : (256 + p*64 + wrow - 64);
#pragma unroll
            for (int i = 0; i < 4; i++) {
                int k8 = ksub + 4*i;
                uint4 wvv = *(const uint4*)(W1 + (size_t)r1 * DD + k8*8);
                *(uint4*)&Wsh[((size_t)k8*128 + wrow) * 8] = wvv;
            }
        }
        __syncthreads();
        f32x4 aa = (f32x4){0.f,0.f,0.f,0.f};
        f32x4 bb = (f32x4){0.f,0.f,0.f,0.f};
#pragma unroll
        for (int kk = 0; kk < 4; kk++) {
            bf16x8 b1v = *(const bf16x8*)&Wsh[(((kk*4 + quad)*128) + ng*16 + l15) * 8];
            bf16x8 b2v = *(const bf16x8*)&Wsh[(((kk*4 + quad)*128) + 64 + ng*16 + l15) * 8];
            aa = __builtin_amdgcn_mfma_f32_16x16x32_bf16(afr[kk], b1v, aa, 0, 0, 0);
            bb = __builtin_amdgcn_mfma_f32_16x16x32_bf16(afr[kk], b2v, bb, 0, 0, 0);
        }
        int n1 = p*64 + ng*16 + l15;
        float ba = b1[n1];
        float bbv = b1[256 + n1];
#pragma unroll
        for (int r = 0; r < 4; r++) {
            float a = aa[r] + ba;
            float bq = bb[r] + bbv;
            int m = mt*16 + quad*4 + r;
            Gsh[m*GPAD + n1] = f2b(siluf(a) * bq);
        }
    }

    f32x4 acc2[2];
    acc2[0] = (f32x4){0.f,0.f,0.f,0.f};
    acc2[1] = (f32x4){0.f,0.f,0.f,0.f};
    for (int kh = 0; kh < 2; kh++) {
        __syncthreads();
        {
            int wrow = tid >> 2, ksub = tid & 3;   // 128 n-rows
#pragma unroll
            for (int i = 0; i < 4; i++) {
                int k8 = ksub + 4*i;
                uint4 wvv = *(const uint4*)(W2 + (size_t)wrow * DI + kh*128 + k8*8);
                *(uint4*)&Wsh[((size_t)k8*128 + wrow) * 8] = wvv;
            }
        }
        __syncthreads();
#pragma unroll
        for (int kk = 0; kk < 4; kk++) {
            bf16x8 af = *(const bf16x8*)&Gsh[(mt*16 + l15)*GPAD + kh*128 + kk*32 + quad*8];
#pragma unroll
            for (int nt = 0; nt < 2; nt++) {
                bf16x8 bfv = *(const bf16x8*)&Wsh[(((kk*4 + quad)*128) + ng*32 + nt*16 + l15) * 8];
                acc2[nt] = __builtin_amdgcn_mfma_f32_16x16x32_bf16(af, bfv, acc2[nt], 0, 0, 0);
            }
        }
    }
#pragma unroll
    for (int nt = 0; nt < 2; nt++) {
        int n = ng*32 + nt*16 + l15;
        float bv = b2[n];
#pragma unroll
        for (int r = 0; r < 4; r++) {
            int lm = mt*16 + quad*4 + r;
            int m = bm + lm;
            float xmv = Xsh[lm*132 + n];
            float v = acc2[nt][r] + bv + xmv;
            Out[(size_t)m * DD + n] = v;
            if (out2) {
                out2[(size_t)m * DD + n] = v;
                out2[(size_t)ML*DD + (size_t)m * DD + n] = xmv;
            }
        }
    }
}

extern "C" void kernel_launch(void* const* d_in, const int* in_sizes, int n_in,
                              void* d_out, int out_size, void* d_ws, size_t ws_size,
                              hipStream_t stream)
{
    (void)in_sizes; (void)n_in; (void)out_size; (void)ws_size;
    const float* x_in      = (const float*)d_in[0];
    const float* ln1_w     = (const float*)d_in[2];
    const float* ln1_b     = (const float*)d_in[3];
    const float* ln2_w     = (const float*)d_in[4];
    const float* ln2_b     = (const float*)d_in[5];
    const float* fc1_w     = (const float*)d_in[6];
    const float* fc1_b     = (const float*)d_in[7];
    const float* fc2_w     = (const float*)d_in[8];
    const float* fc2_b     = (const float*)d_in[9];
    const float* in_proj_w = (const float*)d_in[10];
    const float* conv_w    = (const float*)d_in[11];
    const float* conv_b    = (const float*)d_in[12];
    const float* dt_bias   = (const float*)d_in[13];
    const float* A_log     = (const float*)d_in[14];
    const float* Dp        = (const float*)d_in[15];
    const float* rms_w     = (const float*)d_in[16];
    const float* out_proj_w= (const float*)d_in[17];

    float* ws = (float*)d_ws;
    size_t o = 0;
    float* bufX    = ws + o; o += (size_t)ML * DD;
    float* bufXm   = ws + o; o += (size_t)ML * DD;
    float* bufSegA = ws + o; o += (size_t)BB * NH * SEGS;
    float* bufRL   = ws + o; o += (size_t)ML;
    u16* bufSeg   = (u16*)(ws + o); o += (size_t)BB * NH * SEGS * PP * NNs / 2;  // bf16 state
    u16* bufBigH  = (u16*)(ws + o); o += ((size_t)ML * EE + 1) / 2;
    u16* bufGH    = (u16*)(ws + o); o += (size_t)ML * DI / 2;
    u16* wIpH     = (u16*)(ws + o); o += (IPW_N + 1) / 2;
    u16* wOpH     = (u16*)(ws + o); o += (OPW_N + 1) / 2;
    u16* wF1H     = (u16*)(ws + o); o += (F1W_N + 1) / 2;
    u16* wF2H     = (u16*)(ws + o); o += (F2W_N + 1) / 2;

    cvt_weights<<<CVT_TOT/256, 256, 0, stream>>>(in_proj_w, out_proj_w, fc1_w, fc2_w,
                                                 x_in, wIpH, wOpH, wF1H, wF2H, bufX);

    for (int i = 0; i < NBLK; i++) {
        const float* ln1wi = ln1_w + i * DD;
        const float* ln1bi = ln1_b + i * DD;
        const float* ln2wi = ln2_w + i * DD;
        const float* ln2bi = ln2_b + i * DD;
        const float* cwi   = conv_w + (size_t)i * 320 * 4;
        const float* cbi   = conv_b + (size_t)i * 320;
        const float* dtbi  = dt_bias + i * NH;
        const float* ali   = A_log + i * NH;
        const float* dpi   = Dp + i * NH;
        const float* rwi   = rms_w + (size_t)i * DI;
        const float* f1bi  = fc1_b + (size_t)i * 512;
        const float* f2bi  = fc2_b + (size_t)i * DD;
        const u16* ipwi = wIpH + (size_t)i * EE * DD;
        const u16* opwi = wOpH + (size_t)i * DD * DI;
        const u16* f1wi = wF1H + (size_t)i * 512 * DD;
        const u16* f2wi = wF2H + (size_t)i * DD * DI;

        inproj_ln_gemm<<<dim3(5, ML/64), 256, 0, stream>>>(bufX, ln1wi, ln1bi, ipwi, bufBigH);
        scan1<<<BB*NH*(SEGS/4), 256, 0, stream>>>(bufBigH, cwi, cbi, dtbi, ali, bufSeg, bufSegA);
        scan2<<<BB*NH*8, 256, 0, stream>>>(bufSeg, bufSegA, ali);
        scan3_g<<<BB*SEGS, 256, 0, stream>>>(bufBigH, cwi, cbi, dtbi, ali, bufSeg, dpi,
                                             rwi, bufGH, bufRL);
        grms_outproj_gemm<<<dim3(2, ML/32), 256, 0, stream>>>(bufGH, bufRL, opwi,
                                                              bufX, bufXm);
        mlp_fused<<<ML/32, 512, 0, stream>>>(bufXm, ln2wi, ln2bi, f1wi, f1bi,
                                             f2wi, f2bi, bufX,
                                             (i == NBLK-1) ? (float*)d_out : nullptr);
    }
}

// Round 14
// 775.407 us; speedup vs baseline: 2.3030x; 2.3030x over previous
//
#include <hip/hip_runtime.h>
#include <hip/hip_bf16.h>
#include <cstddef>

// Problem constants
#define NBLK 8
#define DD   128
#define DI   256
#define NH   4
#define PP   64
#define NNs  32
#define EE   580      // D_IN_PROJ
#define BB   2
#define LLEN 4096
#define ML   (BB*LLEN)   // 8192 rows
#define SEGS 256
#define TT   16          // SEGS*TT == LLEN
#define GPAD 264         // padded bf16 row stride

typedef unsigned short u16;
typedef short bf16x8 __attribute__((ext_vector_type(8)));
typedef float f32x4 __attribute__((ext_vector_type(4)));

__device__ __forceinline__ float siluf(float x){ return x / (1.f + expf(-x)); }
__device__ __forceinline__ float b2f(u16 u){ return __uint_as_float((unsigned)u << 16); }
__device__ __forceinline__ u16 f2b(float f){
    __hip_bfloat16 h = __float2bfloat16(f);   // RNE
    return *reinterpret_cast<u16*>(&h);
}
__device__ __forceinline__ void ld8f(const u16* p, float* f){
    ushort4 a = *(const ushort4*)p;
    ushort4 b = *(const ushort4*)(p + 4);
    f[0]=b2f(a.x); f[1]=b2f(a.y); f[2]=b2f(a.z); f[3]=b2f(a.w);
    f[4]=b2f(b.x); f[5]=b2f(b.y); f[6]=b2f(b.z); f[7]=b2f(b.w);
}

// ---------------- weights f32 -> bf16 + x copy (once per launch) ----------------
#define IPW_N (NBLK*EE*DD)
#define OPW_N (NBLK*DD*DI)
#define F1W_N (NBLK*512*DD)
#define F2W_N (NBLK*DD*DI)
#define CVT_TOT (IPW_N+OPW_N+F1W_N+F2W_N)   // 1642496 = 256*6416

__global__ __launch_bounds__(256) void cvt_weights(const float* __restrict__ ip,
                                                   const float* __restrict__ op,
                                                   const float* __restrict__ f1,
                                                   const float* __restrict__ f2,
                                                   const float* __restrict__ xin,
                                                   u16* __restrict__ dip,
                                                   u16* __restrict__ dop,
                                                   u16* __restrict__ df1,
                                                   u16* __restrict__ df2,
                                                   float* __restrict__ xout)
{
    int i = blockIdx.x * 256 + threadIdx.x;
    if (i < IPW_N)                          dip[i] = f2b(ip[i]);
    else if (i < IPW_N + OPW_N)             dop[i - IPW_N] = f2b(op[i - IPW_N]);
    else if (i < IPW_N + OPW_N + F1W_N)     df1[i - IPW_N - OPW_N] = f2b(f1[i - IPW_N - OPW_N]);
    else                                    df2[i - IPW_N - OPW_N - F1W_N] = f2b(f2[i - IPW_N - OPW_N - F1W_N]);
    if (i < ML * DD) xout[i] = xin[i];
}

// ================= Fused LN1 + in_proj GEMM (bf16 out), 2 n-tiles per block =================
// grid (5, ML/64); C[ML][EE] bf16 = LN(X) @ W^T ; K=DD=128
__global__ __launch_bounds__(256) void inproj_ln_gemm(const float* __restrict__ X,
                                                      const float* __restrict__ lnw,
                                                      const float* __restrict__ lnb,
                                                      const u16* __restrict__ W,
                                                      u16* __restrict__ C)
{
    __shared__ __align__(16) u16 Ash[64*128];
    __shared__ __align__(16) u16 Wsh[64*128];
    __shared__ float red[64][8];
    const int tid = threadIdx.x;
    const int wave = tid >> 6, lane = tid & 63;
    const int l15 = lane & 15, quad = lane >> 4;
    const int bm = blockIdx.y * 64;
    const int lrow = tid >> 2, sub = tid & 3;

    // LN prologue (once per block)
    const float* xr = X + (size_t)(bm + lrow) * DD + sub*32;
    float4 xv[8];
    float ps = 0.f, pq = 0.f;
#pragma unroll
    for (int i = 0; i < 8; i++) {
        xv[i] = *(const float4*)(xr + i*4);
        ps += xv[i].x + xv[i].y + xv[i].z + xv[i].w;
        pq += xv[i].x*xv[i].x + xv[i].y*xv[i].y + xv[i].z*xv[i].z + xv[i].w*xv[i].w;
    }
    red[lrow][sub] = ps; red[lrow][4+sub] = pq;
    __syncthreads();
    float s = red[lrow][0]+red[lrow][1]+red[lrow][2]+red[lrow][3];
    float q = red[lrow][4]+red[lrow][5]+red[lrow][6]+red[lrow][7];
    float mu = s * (1.f/DD);
    float rstd = rsqrtf(q*(1.f/DD) - mu*mu + 1e-5f);
#pragma unroll
    for (int i = 0; i < 4; i++) {
        float4 a0 = xv[2*i], a1 = xv[2*i+1];
        int c0 = sub*32 + i*8;
        u16 o[8];
        o[0] = f2b((a0.x-mu)*rstd*lnw[c0+0] + lnb[c0+0]);
        o[1] = f2b((a0.y-mu)*rstd*lnw[c0+1] + lnb[c0+1]);
        o[2] = f2b((a0.z-mu)*rstd*lnw[c0+2] + lnb[c0+2]);
        o[3] = f2b((a0.w-mu)*rstd*lnw[c0+3] + lnb[c0+3]);
        o[4] = f2b((a1.x-mu)*rstd*lnw[c0+4] + lnb[c0+4]);
        o[5] = f2b((a1.y-mu)*rstd*lnw[c0+5] + lnb[c0+5]);
        o[6] = f2b((a1.z-mu)*rstd*lnw[c0+6] + lnb[c0+6]);
        o[7] = f2b((a1.w-mu)*rstd*lnw[c0+7] + lnb[c0+7]);
        *(uint4*)&Ash[((size_t)(sub*4+i)*64 + lrow) * 8] = *(uint4*)o;
    }

    // two n-tiles sharing the LN'd A tile
#pragma unroll 1
    for (int t2 = 0; t2 < 2; t2++) {
        int bn = (blockIdx.x * 2 + t2) * 64;
        __syncthreads();   // Ash ready / prior readers of Wsh done
#pragma unroll
        for (int i = 0; i < 4; i++) {
            int k8 = sub + 4*i;
            uint4 wv = make_uint4(0u,0u,0u,0u);
            if (bn + lrow < EE)
                wv = *(const uint4*)(W + (size_t)(bn + lrow) * DD + k8*8);
            *(uint4*)&Wsh[((size_t)k8*64 + lrow) * 8] = wv;
        }
        __syncthreads();

        f32x4 acc[4];
#pragma unroll
        for (int nt = 0; nt < 4; nt++) acc[nt] = (f32x4){0.f,0.f,0.f,0.f};
#pragma unroll
        for (int kk = 0; kk < 4; kk++) {
            bf16x8 af = *(const bf16x8*)&Ash[(((kk*4 + quad)*64) + wave*16 + l15) * 8];
#pragma unroll
            for (int nt = 0; nt < 4; nt++) {
                bf16x8 bfv = *(const bf16x8*)&Wsh[(((kk*4 + quad)*64) + nt*16 + l15) * 8];
                acc[nt] = __builtin_amdgcn_mfma_f32_16x16x32_bf16(af, bfv, acc[nt], 0, 0, 0);
            }
        }
#pragma unroll
        for (int nt = 0; nt < 4; nt++) {
            int n = bn + nt*16 + l15;
            if (n < EE) {
#pragma unroll
                for (int r = 0; r < 4; r++) {
                    int m = bm + wave*16 + quad*4 + r;
                    C[(size_t)m * EE + n] = f2b(acc[nt][r]);
                }
            }
        }
    }
}

// ================= Scan pass 1: inline conv + local scan, 4 segs/block (bf16 state) =================
__global__ __launch_bounds__(256) void scan1(const u16* __restrict__ zx,
                                             const float* __restrict__ cw,
                                             const float* __restrict__ cb,
                                             const float* __restrict__ dt_bias,
                                             const float* __restrict__ A_log,
                                             u16* __restrict__ seg,
                                             float* __restrict__ segsum)
{
    __shared__ float Bsh[4][TT*NNs];
    __shared__ float dts[4][TT], das[4][TT];
    int wv = threadIdx.x >> 6;
    int p = threadIdx.x & 63;
    int sg = blockIdx.x % (SEGS/4);
    int bh = blockIdx.x / (SEGS/4);
    int h = bh % NH;
    int b = bh / NH;
    int s = sg*4 + wv;
    int l0 = s * TT;
    int row0 = b * LLEN + l0;

    float xr[TT+3];
    const u16* xcol = zx + (size_t)row0 * EE + 256 + h*64 + p;
#pragma unroll
    for (int r = 0; r < TT+3; r++) {
        int l = l0 - 3 + r;
        xr[r] = (l >= 0) ? b2f(xcol[(ptrdiff_t)(r-3) * EE]) : 0.f;
    }
    float4 wx = *(const float4*)(cw + (size_t)(h*64+p) * 4);
    float cbx = cb[h*64+p];

    if (p < NNs) {   // B conv, column p
        float br[TT+3];
        const u16* bcol = zx + (size_t)row0 * EE + 512 + p;
#pragma unroll
        for (int r = 0; r < TT+3; r++) {
            int l = l0 - 3 + r;
            br[r] = (l >= 0) ? b2f(bcol[(ptrdiff_t)(r-3) * EE]) : 0.f;
        }
        float4 wb = *(const float4*)(cw + (size_t)(256+p) * 4);
        float cbb = cb[256+p];
#pragma unroll
        for (int t = 0; t < TT; t++)
            Bsh[wv][t*NNs + p] = siluf(cbb + wb.x*br[t] + wb.y*br[t+1] + wb.z*br[t+2] + wb.w*br[t+3]);
    }
    if (p < TT) {
        float v = b2f(zx[(size_t)(row0+p)*EE + (EE-NH) + h]) + dt_bias[h];
        float dt = (v > 20.f) ? v : log1pf(expf(v));
        dts[wv][p] = dt;
        das[wv][p] = expf(-expf(A_log[h]) * dt);
    }
    __syncthreads();

    float hreg[NNs];
#pragma unroll
    for (int n = 0; n < NNs; n++) hreg[n] = 0.f;
    float sdt = 0.f;
#pragma unroll
    for (int t = 0; t < TT; t++) {
        float dA = das[wv][t];
        float dt = dts[wv][t];
        float xv = siluf(cbx + wx.x*xr[t] + wx.y*xr[t+1] + wx.z*xr[t+2] + wx.w*xr[t+3]);
        float dtx = dt * xv;
#pragma unroll
        for (int n4 = 0; n4 < 8; n4++) {
            float4 Bv = *(const float4*)&Bsh[wv][t*NNs + n4*4];
            hreg[n4*4+0] = fmaf(hreg[n4*4+0], dA, dtx * Bv.x);
            hreg[n4*4+1] = fmaf(hreg[n4*4+1], dA, dtx * Bv.y);
            hreg[n4*4+2] = fmaf(hreg[n4*4+2], dA, dtx * Bv.z);
            hreg[n4*4+3] = fmaf(hreg[n4*4+3], dA, dtx * Bv.w);
        }
        sdt += dt;
    }
    int bidg = bh * SEGS + s;
    u16* dst = seg + ((size_t)bidg * PP + p) * NNs;
#pragma unroll
    for (int n8 = 0; n8 < 4; n8++) {
        u16 ob[8];
#pragma unroll
        for (int j = 0; j < 8; j++) ob[j] = f2b(hreg[n8*8 + j]);
        *(uint4*)(dst + n8*8) = *(uint4*)ob;
    }
    if (p == 0) segsum[bidg] = sdt;
}

// ================= Scan pass 2: cross-segment combine (bf16 state, f32 chain) =================
__global__ __launch_bounds__(256) void scan2(u16* __restrict__ seg,
                                             const float* __restrict__ segsum,
                                             const float* __restrict__ A_log)
{
    int bh = blockIdx.x >> 3;
    int chunk = blockIdx.x & 7;
    int h = bh % NH;
    int entry = chunk * 256 + threadIdx.x;   // 0..2047
    float negA = -expf(A_log[h]);
    float hs = 0.f;
    const float* ss = segsum + bh * SEGS;
    u16* base = seg + (size_t)bh * SEGS * (PP * NNs) + entry;
    for (int j0 = 0; j0 < SEGS; j0 += 16) {
        float e[16], a[16];
#pragma unroll
        for (int k = 0; k < 16; k++) {
            a[k] = ss[j0 + k];
            e[k] = b2f(base[(size_t)(j0 + k) * (PP * NNs)]);
        }
#pragma unroll
        for (int k = 0; k < 16; k++) {
            float Aj = expf(negA * a[k]);
            base[(size_t)(j0 + k) * (PP * NNs)] = f2b(hs);
            hs = fmaf(Aj, hs, e[k]);
        }
    }
}

// ================= Scan pass 3: inline conv, re-scan, emit y (bf16), 4 segs/block =================
__global__ __launch_bounds__(256) void scan3(const u16* __restrict__ zx,
                                             const float* __restrict__ cw,
                                             const float* __restrict__ cb,
                                             const float* __restrict__ dt_bias,
                                             const float* __restrict__ A_log,
                                             const u16* __restrict__ seg,
                                             const float* __restrict__ Dp,
                                             u16* __restrict__ y)
{
    __shared__ float BCsh[4][TT*64];
    __shared__ float dts[4][TT], das[4][TT];
    int wv = threadIdx.x >> 6;
    int p = threadIdx.x & 63;
    int sg = blockIdx.x % (SEGS/4);
    int bh = blockIdx.x / (SEGS/4);
    int h = bh % NH;
    int b = bh / NH;
    int s = sg*4 + wv;
    int l0 = s * TT;
    int row0 = b * LLEN + l0;

    float xr[TT+3];
    const u16* xcol = zx + (size_t)row0 * EE + 256 + h*64 + p;
#pragma unroll
    for (int r = 0; r < TT+3; r++) {
        int l = l0 - 3 + r;
        xr[r] = (l >= 0) ? b2f(xcol[(ptrdiff_t)(r-3) * EE]) : 0.f;
    }
    float4 wx = *(const float4*)(cw + (size_t)(h*64+p) * 4);
    float cbx = cb[h*64+p];

    {   // B/C conv, column p (channel 256+p)
        float br[TT+3];
        const u16* bcol = zx + (size_t)row0 * EE + 512 + p;
#pragma unroll
        for (int r = 0; r < TT+3; r++) {
            int l = l0 - 3 + r;
            br[r] = (l >= 0) ? b2f(bcol[(ptrdiff_t)(r-3) * EE]) : 0.f;
        }
        float4 wb = *(const float4*)(cw + (size_t)(256+p) * 4);
        float cbb = cb[256+p];
#pragma unroll
        for (int t = 0; t < TT; t++)
            BCsh[wv][t*64 + p] = siluf(cbb + wb.x*br[t] + wb.y*br[t+1] + wb.z*br[t+2] + wb.w*br[t+3]);
    }
    if (p < TT) {
        float v = b2f(zx[(size_t)(row0+p)*EE + (EE-NH) + h]) + dt_bias[h];
        float dt = (v > 20.f) ? v : log1pf(expf(v));
        dts[wv][p] = dt;
        das[wv][p] = expf(-expf(A_log[h]) * dt);
    }

    float hreg[NNs];
    int bidg = bh * SEGS + s;
    const u16* src = seg + ((size_t)bidg * PP + p) * NNs;
#pragma unroll
    for (int n8 = 0; n8 < 4; n8++) {
        float f[8];
        ld8f(src + n8*8, f);
#pragma unroll
        for (int j = 0; j < 8; j++) hreg[n8*8 + j] = f[j];
    }
    float dp = Dp[h];
    __syncthreads();

#pragma unroll
    for (int t = 0; t < TT; t++) {
        float dA = das[wv][t];
        float dt = dts[wv][t];
        float xv = siluf(cbx + wx.x*xr[t] + wx.y*xr[t+1] + wx.z*xr[t+2] + wx.w*xr[t+3]);
        float dtx = dt * xv;
        float acc = 0.f;
#pragma unroll
        for (int n4 = 0; n4 < 8; n4++) {
            float4 Bv = *(const float4*)&BCsh[wv][t*64 + n4*4];
            float4 Cv = *(const float4*)&BCsh[wv][t*64 + 32 + n4*4];
            hreg[n4*4+0] = fmaf(hreg[n4*4+0], dA, dtx * Bv.x);
            hreg[n4*4+1] = fmaf(hreg[n4*4+1], dA, dtx * Bv.y);
            hreg[n4*4+2] = fmaf(hreg[n4*4+2], dA, dtx * Bv.z);
            hreg[n4*4+3] = fmaf(hreg[n4*4+3], dA, dtx * Bv.w);
            acc = fmaf(hreg[n4*4+0], Cv.x, acc);
            acc = fmaf(hreg[n4*4+1], Cv.y, acc);
            acc = fmaf(hreg[n4*4+2], Cv.z, acc);
            acc = fmaf(hreg[n4*4+3], Cv.w, acc);
        }
        y[(size_t)(row0 + t) * DI + h*PP + p] = f2b(acc + dp * xv);
    }
}

// ================= Fused gated-RMSNorm + out_proj GEMM (BM=32) =================
// grid (2, ML/32)
__global__ __launch_bounds__(256) void grms_outproj_gemm(const u16* __restrict__ Y,
                                                         const u16* __restrict__ Z,
                                                         const float* __restrict__ rmsw,
                                                         const u16* __restrict__ W,
                                                         const float* __restrict__ resid,
                                                         float* __restrict__ C)
{
    __shared__ __align__(16) u16 Ash[32*256];
    __shared__ __align__(16) u16 Wsh[64*256];
    __shared__ float red[32][8];
    __shared__ float rl[32];
    const int tid = threadIdx.x;
    const int wave = tid >> 6, lane = tid & 63;
    const int l15 = lane & 15, quad = lane >> 4;
    const int rt = wave & 1, nq = wave >> 1;
    const int bm = blockIdx.y * 32;
    const int bn = blockIdx.x * 64;

    {
        int wrow = tid >> 2, ksub = tid & 3;
#pragma unroll
        for (int i = 0; i < 8; i++) {
            int k8 = ksub + 4*i;
            uint4 wv = *(const uint4*)(W + (size_t)(bn + wrow) * DI + k8*8);
            *(uint4*)&Wsh[((size_t)k8*64 + wrow) * 8] = wv;
        }
    }

    int lrow = tid >> 3, sub = tid & 7;
    const u16* yr = Y + (size_t)(bm + lrow) * DI + sub*32;
    const u16* zr = Z + (size_t)(bm + lrow) * EE + sub*32;
    float pq = 0.f;
#pragma unroll
    for (int i = 0; i < 4; i++) {
        float yv[8], zv[8];
        ld8f(yr + i*8, yv);
        ld8f(zr + i*8, zv);
        int c0 = sub*32 + i*8;
        u16 o[8];
#pragma unroll
        for (int j = 0; j < 8; j++) {
            float g = yv[j] * siluf(zv[j]);
            pq += g*g;
            o[j] = f2b(g * rmsw[c0 + j]);
        }
        *(uint4*)&Ash[((size_t)(sub*4 + i)*32 + lrow) * 8] = *(uint4*)o;
    }
    red[lrow][sub] = pq;
    __syncthreads();
    if (sub == 0) {
        float qq = 0.f;
#pragma unroll
        for (int j = 0; j < 8; j++) qq += red[lrow][j];
        rl[lrow] = rsqrtf(qq * (1.f/DI) + 1e-5f);
    }
    __syncthreads();

    f32x4 acc[2];
    acc[0] = (f32x4){0.f,0.f,0.f,0.f};
    acc[1] = (f32x4){0.f,0.f,0.f,0.f};
#pragma unroll
    for (int kk = 0; kk < 8; kk++) {
        bf16x8 af = *(const bf16x8*)&Ash[(((kk*4 + quad)*32) + rt*16 + l15) * 8];
#pragma unroll
        for (int nt = 0; nt < 2; nt++) {
            bf16x8 bfv = *(const bf16x8*)&Wsh[(((kk*4 + quad)*64) + nq*32 + nt*16 + l15) * 8];
            acc[nt] = __builtin_amdgcn_mfma_f32_16x16x32_bf16(af, bfv, acc[nt], 0, 0, 0);
        }
    }
#pragma unroll
    for (int nt = 0; nt < 2; nt++) {
        int n = bn + nq*32 + nt*16 + l15;
#pragma unroll
        for (int r = 0; r < 4; r++) {
            int lm = rt*16 + quad*4 + r;
            int m = bm + lm;
            C[(size_t)m * DD + n] = acc[nt][r] * rl[lm] + resid[(size_t)m * DD + n];
        }
    }
}

// ================= Fused MLP (BM=32, 512 threads / 8 waves), Xm cached in LDS =================
// grid ML/32; wave w: mt = w&1 (m-tile), ng = w>>1 (n-group)
__global__ __launch_bounds__(512) void mlp_fused(const float* __restrict__ Xm,
                                                 const float* __restrict__ lnw,
                                                 const float* __restrict__ lnb,
                                                 const u16* __restrict__ W1,   // 512 x 128
                                                 const float* __restrict__ b1, // 512
                                                 const u16* __restrict__ W2,   // 128 x 256
                                                 const float* __restrict__ b2, // 128
                                                 float* __restrict__ Out,
                                                 float* __restrict__ out2)     // null except last layer
{
    __shared__ __align__(16) u16 Ash[32*128];    // 8 KB
    __shared__ __align__(16) u16 Wsh[128*128];   // 32 KB
    __shared__ __align__(16) u16 Gsh[32*GPAD];   // 16.5 KB
    __shared__ float Xsh[32*132];                // 16.9 KB (Xm cache)
    __shared__ float red[32][32];
    const int tid = threadIdx.x;
    const int wv = tid >> 6, lane = tid & 63;
    const int l15 = lane & 15, quad = lane >> 4;
    const int mt = wv & 1, ng = wv >> 1;
    const int bm = blockIdx.x * 32;

    {
        int lrow = tid >> 4, sub = tid & 15;
        const float* xr = Xm + (size_t)(bm + lrow) * DD + sub*8;
        float4 x0 = *(const float4*)xr;
        float4 x1 = *(const float4*)(xr + 4);
        *(float4*)&Xsh[lrow*132 + sub*8]     = x0;
        *(float4*)&Xsh[lrow*132 + sub*8 + 4] = x1;
        float ps = x0.x+x0.y+x0.z+x0.w + x1.x+x1.y+x1.z+x1.w;
        float pq = x0.x*x0.x+x0.y*x0.y+x0.z*x0.z+x0.w*x0.w
                 + x1.x*x1.x+x1.y*x1.y+x1.z*x1.z+x1.w*x1.w;
        red[lrow][sub] = ps; red[lrow][16+sub] = pq;
        __syncthreads();
        float s = 0.f, q = 0.f;
#pragma unroll
        for (int j = 0; j < 16; j++) { s += red[lrow][j]; q += red[lrow][16+j]; }
        float mu = s * (1.f/DD);
        float rstd = rsqrtf(q*(1.f/DD) - mu*mu + 1e-5f);
        int c0 = sub*8;
        float xa[8] = {x0.x,x0.y,x0.z,x0.w,x1.x,x1.y,x1.z,x1.w};
        u16 o[8];
#pragma unroll
        for (int j = 0; j < 8; j++)
            o[j] = f2b((xa[j]-mu)*rstd*lnw[c0+j] + lnb[c0+j]);
        *(uint4*)&Ash[((size_t)sub*32 + lrow) * 8] = *(uint4*)o;
    }
    __syncthreads();

    bf16x8 afr[4];
#pragma unroll
    for (int kk = 0; kk < 4; kk++)
        afr[kk] = *(const bf16x8*)&Ash[(((kk*4 + quad)*32) + mt*16 + l15) * 8];

    for (int p = 0; p < 4; p++) {
        __syncthreads();
        {
            int wrow = tid >> 2, ksub = tid & 3;   // 128 rows
            int r1 = (wrow < 64) ? (p*64 + wrow) : (256 + p*64 + wrow - 64);
#pragma unroll
            for (int i = 0; i < 4; i++) {
                int k8 = ksub + 4*i;
                uint4 wvv = *(const uint4*)(W1 + (size_t)r1 * DD + k8*8);
                *(uint4*)&Wsh[((size_t)k8*128 + wrow) * 8] = wvv;
            }
        }
        __syncthreads();
        f32x4 aa = (f32x4){0.f,0.f,0.f,0.f};
        f32x4 bb = (f32x4){0.f,0.f,0.f,0.f};
#pragma unroll
        for (int kk = 0; kk < 4; kk++) {
            bf16x8 b1v = *(const bf16x8*)&Wsh[(((kk*4 + quad)*128) + ng*16 + l15) * 8];
            bf16x8 b2v = *(const bf16x8*)&Wsh[(((kk*4 + quad)*128) + 64 + ng*16 + l15) * 8];
            aa = __builtin_amdgcn_mfma_f32_16x16x32_bf16(afr[kk], b1v, aa, 0, 0, 0);
            bb = __builtin_amdgcn_mfma_f32_16x16x32_bf16(afr[kk], b2v, bb, 0, 0, 0);
        }
        int n1 = p*64 + ng*16 + l15;
        float ba = b1[n1];
        float bbv = b1[256 + n1];
#pragma unroll
        for (int r = 0; r < 4; r++) {
            float a = aa[r] + ba;
            float bq = bb[r] + bbv;
            int m = mt*16 + quad*4 + r;
            Gsh[m*GPAD + n1] = f2b(siluf(a) * bq);
        }
    }

    f32x4 acc2[2];
    acc2[0] = (f32x4){0.f,0.f,0.f,0.f};
    acc2[1] = (f32x4){0.f,0.f,0.f,0.f};
    for (int kh = 0; kh < 2; kh++) {
        __syncthreads();
        {
            int wrow = tid >> 2, ksub = tid & 3;   // 128 n-rows
#pragma unroll
            for (int i = 0; i < 4; i++) {
                int k8 = ksub + 4*i;
                uint4 wvv = *(const uint4*)(W2 + (size_t)wrow * DI + kh*128 + k8*8);
                *(uint4*)&Wsh[((size_t)k8*128 + wrow) * 8] = wvv;
            }
        }
        __syncthreads();
#pragma unroll
        for (int kk = 0; kk < 4; kk++) {
            bf16x8 af = *(const bf16x8*)&Gsh[(mt*16 + l15)*GPAD + kh*128 + kk*32 + quad*8];
#pragma unroll
            for (int nt = 0; nt < 2; nt++) {
                bf16x8 bfv = *(const bf16x8*)&Wsh[(((kk*4 + quad)*128) + ng*32 + nt*16 + l15) * 8];
                acc2[nt] = __builtin_amdgcn_mfma_f32_16x16x32_bf16(af, bfv, acc2[nt], 0, 0, 0);
            }
        }
    }
#pragma unroll
    for (int nt = 0; nt < 2; nt++) {
        int n = ng*32 + nt*16 + l15;
        float bv = b2[n];
#pragma unroll
        for (int r = 0; r < 4; r++) {
            int lm = mt*16 + quad*4 + r;
            int m = bm + lm;
            float xmv = Xsh[lm*132 + n];
            float v = acc2[nt][r] + bv + xmv;
            Out[(size_t)m * DD + n] = v;
            if (out2) {
                out2[(size_t)m * DD + n] = v;
                out2[(size_t)ML*DD + (size_t)m * DD + n] = xmv;
            }
        }
    }
}

extern "C" void kernel_launch(void* const* d_in, const int* in_sizes, int n_in,
                              void* d_out, int out_size, void* d_ws, size_t ws_size,
                              hipStream_t stream)
{
    (void)in_sizes; (void)n_in; (void)out_size; (void)ws_size;
    const float* x_in      = (const float*)d_in[0];
    const float* ln1_w     = (const float*)d_in[2];
    const float* ln1_b     = (const float*)d_in[3];
    const float* ln2_w     = (const float*)d_in[4];
    const float* ln2_b     = (const float*)d_in[5];
    const float* fc1_w     = (const float*)d_in[6];
    const float* fc1_b     = (const float*)d_in[7];
    const float* fc2_w     = (const float*)d_in[8];
    const float* fc2_b     = (const float*)d_in[9];
    const float* in_proj_w = (const float*)d_in[10];
    const float* conv_w    = (const float*)d_in[11];
    const float* conv_b    = (const float*)d_in[12];
    const float* dt_bias   = (const float*)d_in[13];
    const float* A_log     = (const float*)d_in[14];
    const float* Dp        = (const float*)d_in[15];
    const float* rms_w     = (const float*)d_in[16];
    const float* out_proj_w= (const float*)d_in[17];

    float* ws = (float*)d_ws;
    size_t o = 0;
    float* bufX    = ws + o; o += (size_t)ML * DD;
    float* bufXm   = ws + o; o += (size_t)ML * DD;
    float* bufSegA = ws + o; o += (size_t)BB * NH * SEGS;
    u16* bufSeg   = (u16*)(ws + o); o += (size_t)BB * NH * SEGS * PP * NNs / 2;  // bf16 state
    u16* bufBigH  = (u16*)(ws + o); o += ((size_t)ML * EE + 1) / 2;
    u16* bufYH    = (u16*)(ws + o); o += (size_t)ML * DI / 2;
    u16* wIpH     = (u16*)(ws + o); o += (IPW_N + 1) / 2;
    u16* wOpH     = (u16*)(ws + o); o += (OPW_N + 1) / 2;
    u16* wF1H     = (u16*)(ws + o); o += (F1W_N + 1) / 2;
    u16* wF2H     = (u16*)(ws + o); o += (F2W_N + 1) / 2;

    cvt_weights<<<CVT_TOT/256, 256, 0, stream>>>(in_proj_w, out_proj_w, fc1_w, fc2_w,
                                                 x_in, wIpH, wOpH, wF1H, wF2H, bufX);

    for (int i = 0; i < NBLK; i++) {
        const float* ln1wi = ln1_w + i * DD;
        const float* ln1bi = ln1_b + i * DD;
        const float* ln2wi = ln2_w + i * DD;
        const float* ln2bi = ln2_b + i * DD;
        const float* cwi   = conv_w + (size_t)i * 320 * 4;
        const float* cbi   = conv_b + (size_t)i * 320;
        const float* dtbi  = dt_bias + i * NH;
        const float* ali   = A_log + i * NH;
        const float* dpi   = Dp + i * NH;
        const float* rwi   = rms_w + (size_t)i * DI;
        const float* f1bi  = fc1_b + (size_t)i * 512;
        const float* f2bi  = fc2_b + (size_t)i * DD;
        const u16* ipwi = wIpH + (size_t)i * EE * DD;
        const u16* opwi = wOpH + (size_t)i * DD * DI;
        const u16* f1wi = wF1H + (size_t)i * 512 * DD;
        const u16* f2wi = wF2H + (size_t)i * DD * DI;

        inproj_ln_gemm<<<dim3(5, ML/64), 256, 0, stream>>>(bufX, ln1wi, ln1bi, ipwi, bufBigH);
        scan1<<<BB*NH*(SEGS/4), 256, 0, stream>>>(bufBigH, cwi, cbi, dtbi, ali, bufSeg, bufSegA);
        scan2<<<BB*NH*8, 256, 0, stream>>>(bufSeg, bufSegA, ali);
        scan3<<<BB*NH*(SEGS/4), 256, 0, stream>>>(bufBigH, cwi, cbi, dtbi, ali, bufSeg, dpi, bufYH);
        grms_outproj_gemm<<<dim3(2, ML/32), 256, 0, stream>>>(bufYH, bufBigH, rwi, opwi,
                                                              bufX, bufXm);
        mlp_fused<<<ML/32, 512, 0, stream>>>(bufXm, ln2wi, ln2bi, f1wi, f1bi,
                                             f2wi, f2bi, bufX,
                                             (i == NBLK-1) ? (float*)d_out : nullptr);
    }
}

// Round 15
// 739.694 us; speedup vs baseline: 2.4142x; 1.0483x over previous
//
#include <hip/hip_runtime.h>
#include <hip/hip_bf16.h>
#include <cstddef>

// Problem constants
#define NBLK 8
#define DD   128
#define DI   256
#define NH   4
#define PP   64
#define NNs  32
#define EE   580      // D_IN_PROJ
#define BB   2
#define LLEN 4096
#define ML   (BB*LLEN)   // 8192 rows
#define SEGS 256
#define TT   16          // SEGS*TT == LLEN
#define GPAD 264         // padded bf16 row stride

typedef unsigned short u16;
typedef short bf16x8 __attribute__((ext_vector_type(8)));
typedef float f32x4 __attribute__((ext_vector_type(4)));

__device__ __forceinline__ float siluf(float x){ return x / (1.f + expf(-x)); }
__device__ __forceinline__ float b2f(u16 u){ return __uint_as_float((unsigned)u << 16); }
__device__ __forceinline__ u16 f2b(float f){
    __hip_bfloat16 h = __float2bfloat16(f);   // RNE
    return *reinterpret_cast<u16*>(&h);
}
__device__ __forceinline__ void ld8f(const u16* p, float* f){
    ushort4 a = *(const ushort4*)p;
    ushort4 b = *(const ushort4*)(p + 4);
    f[0]=b2f(a.x); f[1]=b2f(a.y); f[2]=b2f(a.z); f[3]=b2f(a.w);
    f[4]=b2f(b.x); f[5]=b2f(b.y); f[6]=b2f(b.z); f[7]=b2f(b.w);
}

// ---------------- weights f32 -> bf16 + x copy (once per launch) ----------------
#define IPW_N (NBLK*EE*DD)
#define OPW_N (NBLK*DD*DI)
#define F1W_N (NBLK*512*DD)
#define F2W_N (NBLK*DD*DI)
#define CVT_TOT (IPW_N+OPW_N+F1W_N+F2W_N)   // 1642496 = 256*6416

__global__ __launch_bounds__(256) void cvt_weights(const float* __restrict__ ip,
                                                   const float* __restrict__ op,
                                                   const float* __restrict__ f1,
                                                   const float* __restrict__ f2,
                                                   const float* __restrict__ xin,
                                                   u16* __restrict__ dip,
                                                   u16* __restrict__ dop,
                                                   u16* __restrict__ df1,
                                                   u16* __restrict__ df2,
                                                   float* __restrict__ xout)
{
    int i = blockIdx.x * 256 + threadIdx.x;
    if (i < IPW_N)                          dip[i] = f2b(ip[i]);
    else if (i < IPW_N + OPW_N)             dop[i - IPW_N] = f2b(op[i - IPW_N]);
    else if (i < IPW_N + OPW_N + F1W_N)     df1[i - IPW_N - OPW_N] = f2b(f1[i - IPW_N - OPW_N]);
    else                                    df2[i - IPW_N - OPW_N - F1W_N] = f2b(f2[i - IPW_N - OPW_N - F1W_N]);
    if (i < ML * DD) xout[i] = xin[i];
}

// ================= Fused LN1 + in_proj GEMM (bf16 out), 2 n-tiles per block =================
// grid (5, ML/64); C[ML][EE] bf16 = LN(X) @ W^T ; K=DD=128
__global__ __launch_bounds__(256) void inproj_ln_gemm(const float* __restrict__ X,
                                                      const float* __restrict__ lnw,
                                                      const float* __restrict__ lnb,
                                                      const u16* __restrict__ W,
                                                      u16* __restrict__ C)
{
    __shared__ __align__(16) u16 Ash[64*128];
    __shared__ __align__(16) u16 Wsh[64*128];
    __shared__ float red[64][8];
    const int tid = threadIdx.x;
    const int wave = tid >> 6, lane = tid & 63;
    const int l15 = lane & 15, quad = lane >> 4;
    const int bm = blockIdx.y * 64;
    const int lrow = tid >> 2, sub = tid & 3;

    // LN prologue (once per block)
    const float* xr = X + (size_t)(bm + lrow) * DD + sub*32;
    float4 xv[8];
    float ps = 0.f, pq = 0.f;
#pragma unroll
    for (int i = 0; i < 8; i++) {
        xv[i] = *(const float4*)(xr + i*4);
        ps += xv[i].x + xv[i].y + xv[i].z + xv[i].w;
        pq += xv[i].x*xv[i].x + xv[i].y*xv[i].y + xv[i].z*xv[i].z + xv[i].w*xv[i].w;
    }
    red[lrow][sub] = ps; red[lrow][4+sub] = pq;
    __syncthreads();
    float s = red[lrow][0]+red[lrow][1]+red[lrow][2]+red[lrow][3];
    float q = red[lrow][4]+red[lrow][5]+red[lrow][6]+red[lrow][7];
    float mu = s * (1.f/DD);
    float rstd = rsqrtf(q*(1.f/DD) - mu*mu + 1e-5f);
#pragma unroll
    for (int i = 0; i < 4; i++) {
        float4 a0 = xv[2*i], a1 = xv[2*i+1];
        int c0 = sub*32 + i*8;
        u16 o[8];
        o[0] = f2b((a0.x-mu)*rstd*lnw[c0+0] + lnb[c0+0]);
        o[1] = f2b((a0.y-mu)*rstd*lnw[c0+1] + lnb[c0+1]);
        o[2] = f2b((a0.z-mu)*rstd*lnw[c0+2] + lnb[c0+2]);
        o[3] = f2b((a0.w-mu)*rstd*lnw[c0+3] + lnb[c0+3]);
        o[4] = f2b((a1.x-mu)*rstd*lnw[c0+4] + lnb[c0+4]);
        o[5] = f2b((a1.y-mu)*rstd*lnw[c0+5] + lnb[c0+5]);
        o[6] = f2b((a1.z-mu)*rstd*lnw[c0+6] + lnb[c0+6]);
        o[7] = f2b((a1.w-mu)*rstd*lnw[c0+7] + lnb[c0+7]);
        *(uint4*)&Ash[((size_t)(sub*4+i)*64 + lrow) * 8] = *(uint4*)o;
    }

    // two n-tiles sharing the LN'd A tile
#pragma unroll 1
    for (int t2 = 0; t2 < 2; t2++) {
        int bn = (blockIdx.x * 2 + t2) * 64;
        __syncthreads();   // Ash ready / prior readers of Wsh done
#pragma unroll
        for (int i = 0; i < 4; i++) {
            int k8 = sub + 4*i;
            uint4 wv = make_uint4(0u,0u,0u,0u);
            if (bn + lrow < EE)
                wv = *(const uint4*)(W + (size_t)(bn + lrow) * DD + k8*8);
            *(uint4*)&Wsh[((size_t)k8*64 + lrow) * 8] = wv;
        }
        __syncthreads();

        f32x4 acc[4];
#pragma unroll
        for (int nt = 0; nt < 4; nt++) acc[nt] = (f32x4){0.f,0.f,0.f,0.f};
#pragma unroll
        for (int kk = 0; kk < 4; kk++) {
            bf16x8 af = *(const bf16x8*)&Ash[(((kk*4 + quad)*64) + wave*16 + l15) * 8];
#pragma unroll
            for (int nt = 0; nt < 4; nt++) {
                bf16x8 bfv = *(const bf16x8*)&Wsh[(((kk*4 + quad)*64) + nt*16 + l15) * 8];
                acc[nt] = __builtin_amdgcn_mfma_f32_16x16x32_bf16(af, bfv, acc[nt], 0, 0, 0);
            }
        }
#pragma unroll
        for (int nt = 0; nt < 4; nt++) {
            int n = bn + nt*16 + l15;
            if (n < EE) {
#pragma unroll
                for (int r = 0; r < 4; r++) {
                    int m = bm + wave*16 + quad*4 + r;
                    C[(size_t)m * EE + n] = f2b(acc[nt][r]);
                }
            }
        }
    }
}

// ================= Scan pass 1: inline conv + local scan, 4 segs/block (bf16 state) =================
__global__ __launch_bounds__(256) void scan1(const u16* __restrict__ zx,
                                             const float* __restrict__ cw,
                                             const float* __restrict__ cb,
                                             const float* __restrict__ dt_bias,
                                             const float* __restrict__ A_log,
                                             u16* __restrict__ seg,
                                             float* __restrict__ segsum)
{
    __shared__ float Bsh[4][TT*NNs];
    __shared__ float dts[4][TT], das[4][TT];
    int wv = threadIdx.x >> 6;
    int p = threadIdx.x & 63;
    int sg = blockIdx.x % (SEGS/4);
    int bh = blockIdx.x / (SEGS/4);
    int h = bh % NH;
    int b = bh / NH;
    int s = sg*4 + wv;
    int l0 = s * TT;
    int row0 = b * LLEN + l0;

    float xr[TT+3];
    const u16* xcol = zx + (size_t)row0 * EE + 256 + h*64 + p;
#pragma unroll
    for (int r = 0; r < TT+3; r++) {
        int l = l0 - 3 + r;
        xr[r] = (l >= 0) ? b2f(xcol[(ptrdiff_t)(r-3) * EE]) : 0.f;
    }
    float4 wx = *(const float4*)(cw + (size_t)(h*64+p) * 4);
    float cbx = cb[h*64+p];

    if (p < NNs) {   // B conv, column p
        float br[TT+3];
        const u16* bcol = zx + (size_t)row0 * EE + 512 + p;
#pragma unroll
        for (int r = 0; r < TT+3; r++) {
            int l = l0 - 3 + r;
            br[r] = (l >= 0) ? b2f(bcol[(ptrdiff_t)(r-3) * EE]) : 0.f;
        }
        float4 wb = *(const float4*)(cw + (size_t)(256+p) * 4);
        float cbb = cb[256+p];
#pragma unroll
        for (int t = 0; t < TT; t++)
            Bsh[wv][t*NNs + p] = siluf(cbb + wb.x*br[t] + wb.y*br[t+1] + wb.z*br[t+2] + wb.w*br[t+3]);
    }
    if (p < TT) {
        float v = b2f(zx[(size_t)(row0+p)*EE + (EE-NH) + h]) + dt_bias[h];
        float dt = (v > 20.f) ? v : log1pf(expf(v));
        dts[wv][p] = dt;
        das[wv][p] = expf(-expf(A_log[h]) * dt);
    }
    __syncthreads();

    float hreg[NNs];
#pragma unroll
    for (int n = 0; n < NNs; n++) hreg[n] = 0.f;
    float sdt = 0.f;
#pragma unroll
    for (int t = 0; t < TT; t++) {
        float dA = das[wv][t];
        float dt = dts[wv][t];
        float xv = siluf(cbx + wx.x*xr[t] + wx.y*xr[t+1] + wx.z*xr[t+2] + wx.w*xr[t+3]);
        float dtx = dt * xv;
#pragma unroll
        for (int n4 = 0; n4 < 8; n4++) {
            float4 Bv = *(const float4*)&Bsh[wv][t*NNs + n4*4];
            hreg[n4*4+0] = fmaf(hreg[n4*4+0], dA, dtx * Bv.x);
            hreg[n4*4+1] = fmaf(hreg[n4*4+1], dA, dtx * Bv.y);
            hreg[n4*4+2] = fmaf(hreg[n4*4+2], dA, dtx * Bv.z);
            hreg[n4*4+3] = fmaf(hreg[n4*4+3], dA, dtx * Bv.w);
        }
        sdt += dt;
    }
    int bidg = bh * SEGS + s;
    u16* dst = seg + ((size_t)bidg * PP + p) * NNs;
#pragma unroll
    for (int n8 = 0; n8 < 4; n8++) {
        u16 ob[8];
#pragma unroll
        for (int j = 0; j < 8; j++) ob[j] = f2b(hreg[n8*8 + j]);
        *(uint4*)(dst + n8*8) = *(uint4*)ob;
    }
    if (p == 0) segsum[bidg] = sdt;
}

// ================= Scan pass 2: cross-segment combine (bf16 state, f32 chain) =================
__global__ __launch_bounds__(256) void scan2(u16* __restrict__ seg,
                                             const float* __restrict__ segsum,
                                             const float* __restrict__ A_log)
{
    int bh = blockIdx.x >> 3;
    int chunk = blockIdx.x & 7;
    int h = bh % NH;
    int entry = chunk * 256 + threadIdx.x;   // 0..2047
    float negA = -expf(A_log[h]);
    float hs = 0.f;
    const float* ss = segsum + bh * SEGS;
    u16* base = seg + (size_t)bh * SEGS * (PP * NNs) + entry;
    for (int j0 = 0; j0 < SEGS; j0 += 16) {
        float e[16], a[16];
#pragma unroll
        for (int k = 0; k < 16; k++) {
            a[k] = ss[j0 + k];
            e[k] = b2f(base[(size_t)(j0 + k) * (PP * NNs)]);
        }
#pragma unroll
        for (int k = 0; k < 16; k++) {
            float Aj = expf(negA * a[k]);
            base[(size_t)(j0 + k) * (PP * NNs)] = f2b(hs);
            hs = fmaf(Aj, hs, e[k]);
        }
    }
}

// ================= Scan pass 3: inline conv, re-scan, emit y (bf16), 4 segs/block =================
__global__ __launch_bounds__(256) void scan3(const u16* __restrict__ zx,
                                             const float* __restrict__ cw,
                                             const float* __restrict__ cb,
                                             const float* __restrict__ dt_bias,
                                             const float* __restrict__ A_log,
                                             const u16* __restrict__ seg,
                                             const float* __restrict__ Dp,
                                             u16* __restrict__ y)
{
    __shared__ float BCsh[4][TT*64];
    __shared__ float dts[4][TT], das[4][TT];
    int wv = threadIdx.x >> 6;
    int p = threadIdx.x & 63;
    int sg = blockIdx.x % (SEGS/4);
    int bh = blockIdx.x / (SEGS/4);
    int h = bh % NH;
    int b = bh / NH;
    int s = sg*4 + wv;
    int l0 = s * TT;
    int row0 = b * LLEN + l0;

    float xr[TT+3];
    const u16* xcol = zx + (size_t)row0 * EE + 256 + h*64 + p;
#pragma unroll
    for (int r = 0; r < TT+3; r++) {
        int l = l0 - 3 + r;
        xr[r] = (l >= 0) ? b2f(xcol[(ptrdiff_t)(r-3) * EE]) : 0.f;
    }
    float4 wx = *(const float4*)(cw + (size_t)(h*64+p) * 4);
    float cbx = cb[h*64+p];

    {   // B/C conv, column p (channel 256+p)
        float br[TT+3];
        const u16* bcol = zx + (size_t)row0 * EE + 512 + p;
#pragma unroll
        for (int r = 0; r < TT+3; r++) {
            int l = l0 - 3 + r;
            br[r] = (l >= 0) ? b2f(bcol[(ptrdiff_t)(r-3) * EE]) : 0.f;
        }
        float4 wb = *(const float4*)(cw + (size_t)(256+p) * 4);
        float cbb = cb[256+p];
#pragma unroll
        for (int t = 0; t < TT; t++)
            BCsh[wv][t*64 + p] = siluf(cbb + wb.x*br[t] + wb.y*br[t+1] + wb.z*br[t+2] + wb.w*br[t+3]);
    }
    if (p < TT) {
        float v = b2f(zx[(size_t)(row0+p)*EE + (EE-NH) + h]) + dt_bias[h];
        float dt = (v > 20.f) ? v : log1pf(expf(v));
        dts[wv][p] = dt;
        das[wv][p] = expf(-expf(A_log[h]) * dt);
    }

    float hreg[NNs];
    int bidg = bh * SEGS + s;
    const u16* src = seg + ((size_t)bidg * PP + p) * NNs;
#pragma unroll
    for (int n8 = 0; n8 < 4; n8++) {
        float f[8];
        ld8f(src + n8*8, f);
#pragma unroll
        for (int j = 0; j < 8; j++) hreg[n8*8 + j] = f[j];
    }
    float dp = Dp[h];
    __syncthreads();

#pragma unroll
    for (int t = 0; t < TT; t++) {
        float dA = das[wv][t];
        float dt = dts[wv][t];
        float xv = siluf(cbx + wx.x*xr[t] + wx.y*xr[t+1] + wx.z*xr[t+2] + wx.w*xr[t+3]);
        float dtx = dt * xv;
        float acc = 0.f;
#pragma unroll
        for (int n4 = 0; n4 < 8; n4++) {
            float4 Bv = *(const float4*)&BCsh[wv][t*64 + n4*4];
            float4 Cv = *(const float4*)&BCsh[wv][t*64 + 32 + n4*4];
            hreg[n4*4+0] = fmaf(hreg[n4*4+0], dA, dtx * Bv.x);
            hreg[n4*4+1] = fmaf(hreg[n4*4+1], dA, dtx * Bv.y);
            hreg[n4*4+2] = fmaf(hreg[n4*4+2], dA, dtx * Bv.z);
            hreg[n4*4+3] = fmaf(hreg[n4*4+3], dA, dtx * Bv.w);
            acc = fmaf(hreg[n4*4+0], Cv.x, acc);
            acc = fmaf(hreg[n4*4+1], Cv.y, acc);
            acc = fmaf(hreg[n4*4+2], Cv.z, acc);
            acc = fmaf(hreg[n4*4+3], Cv.w, acc);
        }
        y[(size_t)(row0 + t) * DI + h*PP + p] = f2b(acc + dp * xv);
    }
}

// ================= tail_fused: gating + out_proj + LN2 + fc1/GLU + fc2 (+residuals) =================
// grid ML/32 = 256 blocks x 512 threads (8 waves). Xm lives only in LDS.
// Wave roles: mt = wv&1 (m-tile of 16), ng = wv>>1 (n-group).
__global__ __launch_bounds__(512) void tail_fused(const u16* __restrict__ Y,
                                                  const u16* __restrict__ Z,    // zxbcdt cols 0..255
                                                  const float* __restrict__ rmsw,
                                                  const u16* __restrict__ Wop,  // 128 x 256
                                                  const float* __restrict__ X,  // resid in
                                                  const float* __restrict__ lnw,
                                                  const float* __restrict__ lnb,
                                                  const u16* __restrict__ W1,   // 512 x 128
                                                  const float* __restrict__ b1, // 512
                                                  const u16* __restrict__ W2,   // 128 x 256
                                                  const float* __restrict__ b2, // 128
                                                  float* __restrict__ Out,      // x out
                                                  float* __restrict__ out2)     // d_out or null
{
    // LDS union: Wsh[0,32768) | SH1[32768,49664) (GAsh 16K / Ash2 8K / Gsh 16.9K)
    //            Xsh[49664,66560) 32x132 f32 | red[66560,70656) 32x32 f32 | rl[70656,70784)
    __shared__ __align__(16) unsigned char smem[70784];
    u16*   Wsh = (u16*)smem;
    u16*   SH1 = (u16*)(smem + 32768);
    float* Xsh = (float*)(smem + 49664);
    float (*red)[32] = (float(*)[32])(smem + 66560);
    float* rl  = (float*)(smem + 70656);

    const int tid = threadIdx.x;
    const int wv = tid >> 6, lane = tid & 63;
    const int l15 = lane & 15, quad = lane >> 4;
    const int mt = wv & 1, ng = wv >> 1;      // ng 0..3
    const int bm = blockIdx.x * 32;

    // ---- Phase A1: gating -> GAsh (fragment-major 32 k8-frags x 32 rows) + row sumsq ----
    {
        int lrow = tid >> 4, sub = tid & 15;      // 32 rows x 16 col-chunks of 16
        const u16* yr = Y + (size_t)(bm + lrow) * DI + sub*16;
        const u16* zr = Z + (size_t)(bm + lrow) * EE + sub*16;
        float pq = 0.f;
#pragma unroll
        for (int i = 0; i < 2; i++) {
            float yv[8], zv[8];
            ld8f(yr + i*8, yv);
            ld8f(zr + i*8, zv);
            int c0 = sub*16 + i*8;
            u16 o[8];
#pragma unroll
            for (int j = 0; j < 8; j++) {
                float g = yv[j] * siluf(zv[j]);
                pq += g*g;
                o[j] = f2b(g * rmsw[c0 + j]);
            }
            *(uint4*)&SH1[((size_t)(sub*2 + i)*32 + lrow) * 8] = *(uint4*)o;
        }
        red[lrow][sub] = pq;
    }
    __syncthreads();
    if (tid < 32) {
        float qq = 0.f;
#pragma unroll
        for (int j = 0; j < 16; j++) qq += red[tid][j];
        rl[tid] = rsqrtf(qq * (1.f/DI) + 1e-5f);
    }
    __syncthreads();

    // ---- Phase A2: out_proj in two n-halves of 64; Xm -> Xsh ----
#pragma unroll 1
    for (int nh = 0; nh < 2; nh++) {
        {
            int wrow = tid >> 3, ksub = tid & 7;   // 64 rows x 8 k-subs
#pragma unroll
            for (int i = 0; i < 4; i++) {
                int k8 = ksub + 8*i;               // 0..31
                *(uint4*)&Wsh[((size_t)k8*64 + wrow) * 8] =
                    *(const uint4*)(Wop + (size_t)(nh*64 + wrow) * DI + k8*8);
            }
        }
        __syncthreads();
        f32x4 acc = (f32x4){0.f,0.f,0.f,0.f};
#pragma unroll
        for (int kk = 0; kk < 8; kk++) {
            bf16x8 af = *(const bf16x8*)&SH1[(((kk*4 + quad)*32) + mt*16 + l15) * 8];
            bf16x8 bfv = *(const bf16x8*)&Wsh[(((kk*4 + quad)*64) + ng*16 + l15) * 8];
            acc = __builtin_amdgcn_mfma_f32_16x16x32_bf16(af, bfv, acc, 0, 0, 0);
        }
        int n = nh*64 + ng*16 + l15;
#pragma unroll
        for (int r = 0; r < 4; r++) {
            int lm = mt*16 + quad*4 + r;
            Xsh[lm*132 + n] = acc[r] * rl[lm] + X[(size_t)(bm + lm) * DD + n];
        }
        __syncthreads();
    }

    // ---- Phase B1: LN2 from Xsh -> Ash2 (reuses SH1; GAsh dead) ----
    {
        int lrow = tid >> 4, sub = tid & 15;
        float4 x0 = *(const float4*)&Xsh[lrow*132 + sub*8];
        float4 x1 = *(const float4*)&Xsh[lrow*132 + sub*8 + 4];
        float ps = x0.x+x0.y+x0.z+x0.w + x1.x+x1.y+x1.z+x1.w;
        float pq = x0.x*x0.x+x0.y*x0.y+x0.z*x0.z+x0.w*x0.w
                 + x1.x*x1.x+x1.y*x1.y+x1.z*x1.z+x1.w*x1.w;
        red[lrow][sub] = ps; red[lrow][16+sub] = pq;
        __syncthreads();
        float s = 0.f, q = 0.f;
#pragma unroll
        for (int j = 0; j < 16; j++) { s += red[lrow][j]; q += red[lrow][16+j]; }
        float mu = s * (1.f/DD);
        float rstd = rsqrtf(q*(1.f/DD) - mu*mu + 1e-5f);
        int c0 = sub*8;
        float xa[8] = {x0.x,x0.y,x0.z,x0.w,x1.x,x1.y,x1.z,x1.w};
        u16 o[8];
#pragma unroll
        for (int j = 0; j < 8; j++)
            o[j] = f2b((xa[j]-mu)*rstd*lnw[c0+j] + lnb[c0+j]);
        *(uint4*)&SH1[((size_t)sub*32 + lrow) * 8] = *(uint4*)o;
    }
    __syncthreads();

    bf16x8 afr[4];
#pragma unroll
    for (int kk = 0; kk < 4; kk++)
        afr[kk] = *(const bf16x8*)&SH1[(((kk*4 + quad)*32) + mt*16 + l15) * 8];

    // ---- Phase B2: fc1 + GLU -> Gsh (reuses SH1 after afr cached) ----
    u16* Gsh = SH1;
    for (int p = 0; p < 4; p++) {
        __syncthreads();
        {
            int wrow = tid >> 2, ksub = tid & 3;   // 128 rows
            int r1 = (wrow < 64) ? (p*64 + wrow) : (256 + p*64 + wrow - 64);
#pragma unroll
            for (int i = 0; i < 4; i++) {
                int k8 = ksub + 4*i;
                uint4 wvv = *(const uint4*)(W1 + (size_t)r1 * DD + k8*8);
                *(uint4*)&Wsh[((size_t)k8*128 + wrow) * 8] = wvv;
            }
        }
        __syncthreads();
        f32x4 aa = (f32x4){0.f,0.f,0.f,0.f};
        f32x4 bb = (f32x4){0.f,0.f,0.f,0.f};
#pragma unroll
        for (int kk = 0; kk < 4; kk++) {
            bf16x8 b1v = *(const bf16x8*)&Wsh[(((kk*4 + quad)*128) + ng*16 + l15) * 8];
            bf16x8 b2v = *(const bf16x8*)&Wsh[(((kk*4 + quad)*128) + 64 + ng*16 + l15) * 8];
            aa = __builtin_amdgcn_mfma_f32_16x16x32_bf16(afr[kk], b1v, aa, 0, 0, 0);
            bb = __builtin_amdgcn_mfma_f32_16x16x32_bf16(afr[kk], b2v, bb, 0, 0, 0);
        }
        int n1 = p*64 + ng*16 + l15;
        float ba = b1[n1];
        float bbv = b1[256 + n1];
#pragma unroll
        for (int r = 0; r < 4; r++) {
            float a = aa[r] + ba;
            float bq = bb[r] + bbv;
            int m = mt*16 + quad*4 + r;
            Gsh[m*GPAD + n1] = f2b(siluf(a) * bq);
        }
    }

    // ---- Phase B3: fc2 + residual (from Xsh) ----
    f32x4 acc2[2];
    acc2[0] = (f32x4){0.f,0.f,0.f,0.f};
    acc2[1] = (f32x4){0.f,0.f,0.f,0.f};
    for (int kh = 0; kh < 2; kh++) {
        __syncthreads();
        {
            int wrow = tid >> 2, ksub = tid & 3;   // 128 n-rows
#pragma unroll
            for (int i = 0; i < 4; i++) {
                int k8 = ksub + 4*i;
                uint4 wvv = *(const uint4*)(W2 + (size_t)wrow * DI + kh*128 + k8*8);
                *(uint4*)&Wsh[((size_t)k8*128 + wrow) * 8] = wvv;
            }
        }
        __syncthreads();
#pragma unroll
        for (int kk = 0; kk < 4; kk++) {
            bf16x8 af = *(const bf16x8*)&Gsh[(mt*16 + l15)*GPAD + kh*128 + kk*32 + quad*8];
#pragma unroll
            for (int nt = 0; nt < 2; nt++) {
                bf16x8 bfv = *(const bf16x8*)&Wsh[(((kk*4 + quad)*128) + ng*32 + nt*16 + l15) * 8];
                acc2[nt] = __builtin_amdgcn_mfma_f32_16x16x32_bf16(af, bfv, acc2[nt], 0, 0, 0);
            }
        }
    }
#pragma unroll
    for (int nt = 0; nt < 2; nt++) {
        int n = ng*32 + nt*16 + l15;
        float bv = b2[n];
#pragma unroll
        for (int r = 0; r < 4; r++) {
            int lm = mt*16 + quad*4 + r;
            int m = bm + lm;
            float xmv = Xsh[lm*132 + n];
            float v = acc2[nt][r] + bv + xmv;
            Out[(size_t)m * DD + n] = v;
            if (out2) {
                out2[(size_t)m * DD + n] = v;
                out2[(size_t)ML*DD + (size_t)m * DD + n] = xmv;
            }
        }
    }
}

extern "C" void kernel_launch(void* const* d_in, const int* in_sizes, int n_in,
                              void* d_out, int out_size, void* d_ws, size_t ws_size,
                              hipStream_t stream)
{
    (void)in_sizes; (void)n_in; (void)out_size; (void)ws_size;
    const float* x_in      = (const float*)d_in[0];
    const float* ln1_w     = (const float*)d_in[2];
    const float* ln1_b     = (const float*)d_in[3];
    const float* ln2_w     = (const float*)d_in[4];
    const float* ln2_b     = (const float*)d_in[5];
    const float* fc1_w     = (const float*)d_in[6];
    const float* fc1_b     = (const float*)d_in[7];
    const float* fc2_w     = (const float*)d_in[8];
    const float* fc2_b     = (const float*)d_in[9];
    const float* in_proj_w = (const float*)d_in[10];
    const float* conv_w    = (const float*)d_in[11];
    const float* conv_b    = (const float*)d_in[12];
    const float* dt_bias   = (const float*)d_in[13];
    const float* A_log     = (const float*)d_in[14];
    const float* Dp        = (const float*)d_in[15];
    const float* rms_w     = (const float*)d_in[16];
    const float* out_proj_w= (const float*)d_in[17];

    float* ws = (float*)d_ws;
    size_t o = 0;
    float* bufX    = ws + o; o += (size_t)ML * DD;
    float* bufSegA = ws + o; o += (size_t)BB * NH * SEGS;
    u16* bufSeg   = (u16*)(ws + o); o += (size_t)BB * NH * SEGS * PP * NNs / 2;  // bf16 state
    u16* bufBigH  = (u16*)(ws + o); o += ((size_t)ML * EE + 1) / 2;
    u16* bufYH    = (u16*)(ws + o); o += (size_t)ML * DI / 2;
    u16* wIpH     = (u16*)(ws + o); o += (IPW_N + 1) / 2;
    u16* wOpH     = (u16*)(ws + o); o += (OPW_N + 1) / 2;
    u16* wF1H     = (u16*)(ws + o); o += (F1W_N + 1) / 2;
    u16* wF2H     = (u16*)(ws + o); o += (F2W_N + 1) / 2;

    cvt_weights<<<CVT_TOT/256, 256, 0, stream>>>(in_proj_w, out_proj_w, fc1_w, fc2_w,
                                                 x_in, wIpH, wOpH, wF1H, wF2H, bufX);

    for (int i = 0; i < NBLK; i++) {
        const float* ln1wi = ln1_w + i * DD;
        const float* ln1bi = ln1_b + i * DD;
        const float* ln2wi = ln2_w + i * DD;
        const float* ln2bi = ln2_b + i * DD;
        const float* cwi   = conv_w + (size_t)i * 320 * 4;
        const float* cbi   = conv_b + (size_t)i * 320;
        const float* dtbi  = dt_bias + i * NH;
        const float* ali   = A_log + i * NH;
        const float* dpi   = Dp + i * NH;
        const float* rwi   = rms_w + (size_t)i * DI;
        const float* f1bi  = fc1_b + (size_t)i * 512;
        const float* f2bi  = fc2_b + (size_t)i * DD;
        const u16* ipwi = wIpH + (size_t)i * EE * DD;
        const u16* opwi = wOpH + (size_t)i * DD * DI;
        const u16* f1wi = wF1H + (size_t)i * 512 * DD;
        const u16* f2wi = wF2H + (size_t)i * DD * DI;

        inproj_ln_gemm<<<dim3(5, ML/64), 256, 0, stream>>>(bufX, ln1wi, ln1bi, ipwi, bufBigH);
        scan1<<<BB*NH*(SEGS/4), 256, 0, stream>>>(bufBigH, cwi, cbi, dtbi, ali, bufSeg, bufSegA);
        scan2<<<BB*NH*8, 256, 0, stream>>>(bufSeg, bufSegA, ali);
        scan3<<<BB*NH*(SEGS/4), 256, 0, stream>>>(bufBigH, cwi, cbi, dtbi, ali, bufSeg, dpi, bufYH);
        tail_fused<<<ML/32, 512, 0, stream>>>(bufYH, bufBigH, rwi, opwi, bufX,
                                              ln2wi, ln2bi, f1wi, f1bi, f2wi, f2bi,
                                              bufX, (i == NBLK-1) ? (float*)d_out : nullptr);
    }
}